// Round 10
// baseline (85.853 us; speedup 1.0000x reference)
//
#include <hip/hip_runtime.h>
#include <hip/hip_bf16.h>
#include <string.h>

#define N 4096
#define D 512
#define NB 64            // N/64 regions; triangle regions = NB*(NB+1)/2 = 2080
#define NBLK (NB*(NB+1)/2)
#define MARGIN 0.5f
#define FINF __builtin_huge_valf()
#define UINF 0x7F800000u

typedef __attribute__((ext_vector_type(4))) float f32x4;
typedef long fp8x8;      // 8 packed fp8-e4m3 (i64 MFMA operand)

__device__ inline float wave_sum(float v){
  #pragma unroll
  for (int off=32; off>0; off>>=1) v += __shfl_down(v, off, 64);
  return v;
}

// Pass 0: X (f32) -> fp8 e4m3 (2 MB panel), f32 row squared norms,
// init the atomic min/max arrays.
__global__ __launch_bounds__(128) void prep_kernel(const float* __restrict__ X,
    unsigned char* __restrict__ Xq, float* __restrict__ sq,
    unsigned int* __restrict__ hp2u, unsigned int* __restrict__ nm2u){
  const int row = blockIdx.x;
  const int t = threadIdx.x;
  const float4 v = *(const float4*)(X + (size_t)row*D + t*4);
  int p0 = __builtin_amdgcn_cvt_pk_fp8_f32(v.x, v.y, 0, false);
  int p1 = __builtin_amdgcn_cvt_pk_fp8_f32(v.z, v.w, 0, false);
  unsigned int packed = (p0 & 0xFFFFu) | ((unsigned int)(p1 & 0xFFFFu) << 16);
  *(unsigned int*)(Xq + (size_t)row*D + t*4) = packed;
  float ss = v.x*v.x + v.y*v.y + v.z*v.z + v.w*v.w;
  ss = wave_sum(ss);
  __shared__ float red[2];
  if ((t & 63) == 0) red[t >> 6] = ss;
  __syncthreads();
  if (t == 0){
    sq[row] = red[0] + red[1];
    hp2u[row] = 0u;                 // max-accumulator (d^2 domain, >= 0)
    nm2u[row] = UINF;               // +inf: min-accumulator
  }
}

// Fused triangle GEMM (fp8 MFMA, 64x64 tiles) + hardest-pos/neg reductions.
// 2080 blocks (~8/CU by grid, 4 resident via launch_bounds) so barrier drains
// overlap with other blocks' compute. BK=128: 4 K-slabs x 2 barriers.
// XOR-swizzled 16B LDS slots (R9's measured-conflict-free scheme, 8 slots/row).
__global__ __launch_bounds__(256,4) void gemm_fused(const unsigned char* __restrict__ Xq,
    const float* __restrict__ sq, const int* __restrict__ lab,
    unsigned int* __restrict__ hp2u, unsigned int* __restrict__ nm2u){
  __shared__ __align__(16) unsigned char As[64*128];   // 8 KB
  __shared__ __align__(16) unsigned char Bs[64*128];   // 8 KB
  __shared__ float sqi[64];
  __shared__ float sqj[64];
  __shared__ int labi_s[64];
  __shared__ int labj_s[64];
  __shared__ unsigned int hpl[64], nml[64];   // region-row combine
  __shared__ unsigned int hpc[64], nmc[64];   // region-col combine

  // XCD-contiguous mapping: XCD x gets regions [x*260, (x+1)*260) of the triangle.
  const int rid = (blockIdx.x & 7) * (NBLK/8) + (blockIdx.x >> 3);
  int rem = rid, bi = 0;
  while (rem >= NB - bi){ rem -= NB - bi; bi++; }
  const int bj = bi + rem;
  const int row0 = bi * 64, col0 = bj * 64;

  const int tid = threadIdx.x;
  const int wave = tid >> 6, lane = tid & 63;
  const int wr = (wave >> 1) * 32, wc = (wave & 1) * 32;   // wave's 32x32 quadrant
  const int fr = lane & 15, q = lane >> 4;

  if (tid < 64) {
    sqi[tid] = sq[row0 + tid]; sqj[tid] = sq[col0 + tid];
    labi_s[tid] = lab[row0 + tid]; labj_s[tid] = lab[col0 + tid];
    hpl[tid] = 0u; nml[tid] = UINF; hpc[tid] = 0u; nmc[tid] = UINF;
  }

  // Staging: rows are 128 B = 8 x 16B slots. LDS slot s of row r holds global
  // chunk g = s ^ (r&7). Per issue a wave covers 8 rows x 8 chunks (1 KB):
  // lane l -> local row lr = l>>3, slot = l&7, fetches chunk g = (l&7) ^ lr.
  const int lr  = lane >> 3;
  const int gch = (lane & 7) ^ lr;
  const unsigned char* gA = Xq + (size_t)(row0 + wave*16 + lr)*D + gch*16;
  const unsigned char* gB = Xq + (size_t)(col0 + wave*16 + lr)*D + gch*16;

  f32x4 acc[2][2];
  #pragma unroll
  for (int a=0;a<2;a++)
    #pragma unroll
    for (int b=0;b<2;b++)
      acc[a][b] = (f32x4){0.f,0.f,0.f,0.f};

  for (int it = 0; it < D/128; ++it){
    const int k0 = it * 128;
    __syncthreads();   // previous slab's ds_reads done before overwrite
    #pragma unroll
    for (int c=0;c<2;c++){
      const int rg = wave*16 + c*8;    // wave-uniform 8-row group
      __builtin_amdgcn_global_load_lds(
          (const __attribute__((address_space(1))) void*)(gA + (size_t)c*8*D + k0),
          (__attribute__((address_space(3))) void*)(As + rg*128), 16, 0, 0);
      __builtin_amdgcn_global_load_lds(
          (const __attribute__((address_space(1))) void*)(gB + (size_t)c*8*D + k0),
          (__attribute__((address_space(3))) void*)(Bs + rg*128), 16, 0, 0);
    }
    __syncthreads();   // compiler drains vmcnt before barrier -> LDS valid

    // Fragments: A[m=fr][k = kb*32 + q*8 + j]; chunk c = kb*2 + (q>>1),
    // swizzled slot = c ^ (r&7), 8 B at intra-offset (q&1)*8.
    #pragma unroll
    for (int kb=0;kb<4;kb++){
      const int cch = kb*2 + (q>>1);
      const int hb = (q&1)*8;
      fp8x8 af[2], bf[2];
      #pragma unroll
      for (int a=0;a<2;a++){
        const int ra = wr + a*16 + fr;
        af[a] = *(const fp8x8*)(As + ra*128 + ((cch ^ (ra&7))*16) + hb);
      }
      #pragma unroll
      for (int b=0;b<2;b++){
        const int rb = wc + b*16 + fr;
        bf[b] = *(const fp8x8*)(Bs + rb*128 + ((cch ^ (rb&7))*16) + hb);
      }
      #pragma unroll
      for (int a=0;a<2;a++)
        #pragma unroll
        for (int b=0;b<2;b++)
          acc[a][b] = __builtin_amdgcn_mfma_f32_16x16x32_fp8_fp8(af[a], bf[b], acc[a][b], 0, 0, 0);
    }
  }

  // Epilogue. C/D layout: col=lane&15, row=(lane>>4)*4+v (shape-determined).
  const int colq = lane & 15, g4 = lane >> 4, rowq = g4 * 4;
  int   labi_r[8]; float sqi_r[8];
  #pragma unroll
  for (int a=0;a<2;a++)
    #pragma unroll
    for (int v=0;v<4;v++){
      const int iloc = wr + a*16 + rowq + v;
      labi_r[a*4+v] = labi_s[iloc];
      sqi_r[a*4+v]  = sqi[iloc];
    }

  float pmax_r[8], nmin_r[8];
  #pragma unroll
  for (int k=0;k<8;k++){ pmax_r[k] = 0.f; nmin_r[k] = FINF; }
  float cpos[2], cmin[2];

  #pragma unroll
  for (int b=0;b<2;b++){
    const int jloc = wc + b*16 + colq;
    const float sj = sqj[jloc];
    const int lj = labj_s[jloc];
    float cp = 0.f, cn = FINF;
    #pragma unroll
    for (int a=0;a<2;a++)
      #pragma unroll
      for (int v=0;v<4;v++){
        const int k = a*4+v;
        const float d2 = fmaf(acc[a][b][v], -2.0f, sqi_r[k] + sj);
        const bool same = (labi_r[k] == lj);         // covers diag (i==j)
        const float sp = same ? d2 : 0.0f;           // positive candidate
        const float sn = same ? FINF : d2;           // negative candidate
        pmax_r[k] = fmaxf(pmax_r[k], sp);
        nmin_r[k] = fminf(nmin_r[k], sn);
        cp = fmaxf(cp, sp);
        cn = fminf(cn, sn);
      }
    cpos[b] = cp; cmin[b] = cn;
  }

  // Row-direction: xor-reduce across the 16 lanes sharing a row -> LDS atomic.
  #pragma unroll
  for (int k=0;k<8;k++){
    float p = pmax_r[k], n = nmin_r[k];
    #pragma unroll
    for (int m=1;m<16;m<<=1){
      p = fmaxf(p, __shfl_xor(p, m, 64));
      n = fminf(n, __shfl_xor(n, m, 64));
    }
    if (colq == 0){
      const int il = wr + (k>>2)*16 + rowq + (k&3);
      atomicMax(&hpl[il], __float_as_uint(p));                 // p >= 0
      atomicMin(&nml[il], __float_as_uint(fmaxf(n, 0.f)));     // clamp: monotone
    }
  }
  // Column-direction (symmetry): xor-reduce across the 4 lane-groups -> LDS atomic.
  #pragma unroll
  for (int b=0;b<2;b++){
    float p = cpos[b], n = cmin[b];
    p = fmaxf(p, __shfl_xor(p, 16, 64)); p = fmaxf(p, __shfl_xor(p, 32, 64));
    n = fminf(n, __shfl_xor(n, 16, 64)); n = fminf(n, __shfl_xor(n, 32, 64));
    if (g4 == 0){
      const int jl = wc + b*16 + colq;
      atomicMax(&hpc[jl], __float_as_uint(p));
      atomicMin(&nmc[jl], __float_as_uint(fmaxf(n, 0.f)));
    }
  }

  __syncthreads();
  // Global flush: threads 0-63 do region rows, 64-127 region cols.
  if (tid < 64){
    atomicMax(hp2u + row0 + tid, hpl[tid]);
    atomicMin(nm2u + row0 + tid, nml[tid]);
  } else if (tid < 128){
    const int t2 = tid - 64;
    atomicMax(hp2u + col0 + t2, hpc[t2]);
    atomicMin(nm2u + col0 + t2, nmc[t2]);
  }
}

// Final: loss = mean(sqrt(hp2)) + mean(max(margin - sqrt(nm2), 0)).
// Separate dispatch: kernel boundary guarantees atomics' visibility.
__global__ __launch_bounds__(256) void final_reduce(const uint4* __restrict__ hp2u4,
    const uint4* __restrict__ nm2u4, float* __restrict__ out){
  float s = 0.f;
  #pragma unroll
  for (int it = 0; it < 4; ++it){
    const int i = threadIdx.x + it * 256;
    const uint4 h4 = hp2u4[i];
    const uint4 n4 = nm2u4[i];
    const unsigned int hw[4] = {h4.x, h4.y, h4.z, h4.w};
    const unsigned int nw[4] = {n4.x, n4.y, n4.z, n4.w};
    #pragma unroll
    for (int j=0;j<4;j++){
      s += sqrtf(__uint_as_float(hw[j]) + 1e-12f)
         + fmaxf(MARGIN - sqrtf(__uint_as_float(nw[j]) + 1e-12f), 0.f);
    }
  }
  s = wave_sum(s);
  __shared__ float r[4];
  if ((threadIdx.x & 63) == 0) r[threadIdx.x >> 6] = s;
  __syncthreads();
  if (threadIdx.x == 0) out[0] = (r[0] + r[1] + r[2] + r[3]) * (1.0f / (float)N);
}

extern "C" void kernel_launch(void* const* d_in, const int* in_sizes, int n_in,
                              void* d_out, int out_size, void* d_ws, size_t ws_size,
                              hipStream_t stream) {
  (void)in_sizes; (void)n_in; (void)out_size; (void)ws_size;
  const float* X  = (const float*)d_in[0];
  const int* lab  = (const int*)d_in[1];
  float* out      = (float*)d_out;

  char* ws = (char*)d_ws;
  unsigned char* Xq     = (unsigned char*)ws;                  // 2 MB fp8
  float* sq             = (float*)(Xq + (size_t)N * D);        // 16 KB
  unsigned int* hp2u    = (unsigned int*)(sq + N);             // 16 KB
  unsigned int* nm2u    = hp2u + N;                            // 16 KB

  prep_kernel<<<N, 128, 0, stream>>>(X, Xq, sq, hp2u, nm2u);
  gemm_fused<<<NBLK, 256, 0, stream>>>(Xq, sq, lab, hp2u, nm2u);
  final_reduce<<<1, 256, 0, stream>>>((const uint4*)hp2u, (const uint4*)nm2u, out);
}